// Round 10
// baseline (251.747 us; speedup 1.0000x reference)
//
#include <hip/hip_runtime.h>
#include <hip/hip_cooperative_groups.h>
#include <math.h>

namespace cg = cooperative_groups;

#define M_ROWS 8192   // B*S
#define KDIM   8192   // V
#define NDIM   512    // D
#define RCAP   512    // LDS list slots per row (mean nnz 82, sigma 9)
#define NBLK   512    // 2 blocks/CU, co-resident (cooperative requirement)
#define RPB    16     // rows per block; 4 waves -> 4 rows per wave

typedef float    f32x4  __attribute__((ext_vector_type(4)));
typedef unsigned u32x4  __attribute__((ext_vector_type(4)));
typedef __bf16   bf16x8 __attribute__((ext_vector_type(8)));

// One cooperative kernel, three grid-aligned phases:
//  A: transpose W -> WT bf16 [8192][512] (2 tiles/block) + scan 4 rows/wave,
//     ballot-compacting (bf16val<<16 | v) into per-row LDS lists.
//  B: gather WT rows with v < 4096  (4 MB slice -> per-XCD-L2-resident)
//  C: gather WT rows with v >= 4096 (other 4 MB slice), tanh, store.
// Register accumulators persist across grid.sync() -> zero partial-C traffic.
// Exact at any density: lists enumerate actual nonzeros; overflow (never at
// ~1%) -> sentinel -> exact re-scan fallback in phase C.
__global__ __launch_bounds__(256, 2)
void spmm_coop(const float* __restrict__ A, const float* __restrict__ W,
               __bf16* __restrict__ WT, float* __restrict__ C) {
  __shared__ __align__(16) unsigned shmem[RPB * RCAP];   // 32 KB
  const int tid  = threadIdx.x;
  const int lane = tid & 63;
  const int w    = tid >> 6;
  cg::grid_group grid = cg::this_grid();
  const char* wtb = (const char*)WT;

#define FMA8(r, f, q)                                                       \
  { acc[r][0] = fmaf(f, __uint_as_float((q).x << 16),        acc[r][0]);    \
    acc[r][1] = fmaf(f, __uint_as_float((q).x & 0xffff0000u), acc[r][1]);   \
    acc[r][2] = fmaf(f, __uint_as_float((q).y << 16),        acc[r][2]);    \
    acc[r][3] = fmaf(f, __uint_as_float((q).y & 0xffff0000u), acc[r][3]);   \
    acc[r][4] = fmaf(f, __uint_as_float((q).z << 16),        acc[r][4]);    \
    acc[r][5] = fmaf(f, __uint_as_float((q).z & 0xffff0000u), acc[r][5]);   \
    acc[r][6] = fmaf(f, __uint_as_float((q).w << 16),        acc[r][6]);    \
    acc[r][7] = fmaf(f, __uint_as_float((q).w & 0xffff0000u), acc[r][7]); }

#define GATHER_RANGE(r, rl, beg, end)                                       \
  for (int g = (beg); g < (end); g += 8) {                                  \
    unsigned pk[8]; u32x4 qv[8];                                            \
    _Pragma("unroll")                                                       \
    for (int k = 0; k < 8; ++k)                                             \
      pk[k] = (g + k < (end)) ? (rl)[g + k] : 0u;  /* pad: f=0 adds 0 */    \
    _Pragma("unroll")                                                       \
    for (int k = 0; k < 8; ++k)                                             \
      qv[k] = *(const u32x4*)(wtb + (size_t)(pk[k] & 8191u) * (NDIM * 2)    \
                              + lane * 16);                                 \
    _Pragma("unroll")                                                       \
    for (int k = 0; k < 8; ++k) {                                           \
      float f = __uint_as_float(pk[k] & 0xFFFF0000u);                       \
      FMA8(r, f, qv[k]);                                                    \
    }                                                                       \
  }

  // ============ Phase A1: transpose two 64x64 W-tiles ============
  {
    float (*tile)[65] = (float(*)[65])shmem;       // 16.6 KB alias
    #pragma unroll
    for (int tt = 0; tt < 2; ++tt) {
      const int tl = blockIdx.x * 2 + tt;          // 1024 tiles total
      const int v0 = (tl & 127) << 6;
      const int d0 = (tl >> 7) << 6;
      #pragma unroll
      for (int i = 0; i < 4; ++i) {
        int idx = i * 256 + tid;
        int r = idx >> 4, c = (idx & 15) << 2;
        f32x4 val = __builtin_nontemporal_load(
            (const f32x4*)(W + (size_t)(d0 + r) * KDIM + v0 + c));
        tile[r][c + 0] = val.x; tile[r][c + 1] = val.y;
        tile[r][c + 2] = val.z; tile[r][c + 3] = val.w;
      }
      __syncthreads();
      #pragma unroll
      for (int i = 0; i < 2; ++i) {
        int idx = i * 256 + tid;
        int vr = idx >> 3, d8 = (idx & 7) << 3;
        bf16x8 u;
        #pragma unroll
        for (int j = 0; j < 8; ++j) u[j] = (__bf16)tile[d8 + j][vr];
        *(bf16x8*)(WT + (size_t)(v0 + vr) * NDIM + d0 + d8) = u;
      }
      __syncthreads();
    }
  }

  // ============ Phase A2: scan 4 rows/wave -> LDS lists ============
  unsigned (*lists)[RCAP] = (unsigned(*)[RCAP])shmem;
  unsigned meta[4];
  const unsigned long long ltmask = (1ull << lane) - 1ull;
  #pragma unroll
  for (int r = 0; r < 4; ++r) {
    const int lrow = w * 4 + r;
    const int m = blockIdx.x * RPB + lrow;
    const float* arow = A + (size_t)m * KDIM;
    unsigned* rl = &lists[lrow][0];
    unsigned cur = 0, nlo = 0;
    bool ovf = false;
    f32x4 bufs[8];                                  // 8-deep rotating prefetch
    #pragma unroll
    for (int p = 0; p < 8; ++p)
      bufs[p] = __builtin_nontemporal_load(
          (const f32x4*)(arow + p * 256 + lane * 4));
    #pragma unroll 8
    for (int pos = 0; pos < 32; ++pos) {
      f32x4 av = bufs[pos & 7];
      if (pos + 8 < 32)
        bufs[pos & 7] = __builtin_nontemporal_load(
            (const f32x4*)(arow + (pos + 8) * 256 + lane * 4));
      #pragma unroll
      for (int j = 0; j < 4; ++j) {
        unsigned long long msk = __ballot(av[j] != 0.0f);
        if (msk == 0) continue;
        unsigned cnt = (unsigned)__popcll(msk);
        if (cur + cnt <= RCAP) {
          if (av[j] != 0.0f) {
            unsigned pre = (unsigned)__popcll(msk & ltmask);
            unsigned fb  = (__float_as_uint(av[j]) + 0x8000u) & 0xFFFF0000u;
            rl[cur + pre] = fb | (unsigned)(pos * 256 + lane * 4 + j);
          }
          cur += cnt;
        } else {
          ovf = true;                               // ~never at 1% density
        }
      }
      if (pos == 15) nlo = cur;                     // v-half split point
    }
    meta[r] = ovf ? 0xFFFFFFFFu : (nlo | (cur << 16));
  }

  grid.sync();   // lists + WT complete; grid phase-aligned for slice 0

  // ============ Phase B: gather v < 4096 (L2-resident slice) ============
  float acc[4][8];
  #pragma unroll
  for (int r = 0; r < 4; ++r)
    #pragma unroll
    for (int j = 0; j < 8; ++j) acc[r][j] = 0.f;

  #pragma unroll
  for (int r = 0; r < 4; ++r) {
    const unsigned* rl = &lists[w * 4 + r][0];
    if (meta[r] == 0xFFFFFFFFu) continue;           // fallback handled in C
    const int nlo = (int)(meta[r] & 0xFFFFu);
    GATHER_RANGE(r, rl, 0, nlo);
  }

  grid.sync();   // grid phase-aligned for slice 1

  // ============ Phase C: gather v >= 4096, tanh, store ============
  #pragma unroll
  for (int r = 0; r < 4; ++r) {
    const int lrow = w * 4 + r;
    const int m = blockIdx.x * RPB + lrow;
    const unsigned* rl = &lists[lrow][0];
    if (meta[r] == 0xFFFFFFFFu) {
      // exact fallback: full re-scan of the row (B skipped it; acc == 0)
      const float* arow = A + (size_t)m * KDIM;
      for (int it = 0; it < KDIM / 256; ++it) {
        f32x4 av = *(const f32x4*)(arow + it * 256 + lane * 4);
        #pragma unroll
        for (int j = 0; j < 4; ++j) {
          unsigned long long msk = __ballot(av[j] != 0.0f);
          while (msk) {
            int s = __builtin_ctzll(msk); msk &= msk - 1;
            float f = __shfl(av[j], s, 64);
            int v = it * 256 + s * 4 + j;
            u32x4 q = *(const u32x4*)(wtb + (size_t)v * (NDIM * 2) + lane * 16);
            FMA8(r, f, q);
          }
        }
      }
    } else {
      const int nlo = (int)(meta[r] & 0xFFFFu);
      const int tot = (int)(meta[r] >> 16);
      GATHER_RANGE(r, rl, nlo, tot);
    }
    float* crow = C + (size_t)m * NDIM + lane * 8;
    f32x4 o0 = {tanhf(acc[r][0]), tanhf(acc[r][1]),
                tanhf(acc[r][2]), tanhf(acc[r][3])};
    f32x4 o1 = {tanhf(acc[r][4]), tanhf(acc[r][5]),
                tanhf(acc[r][6]), tanhf(acc[r][7])};
    __builtin_nontemporal_store(o0, (f32x4*)(crow + 0));
    __builtin_nontemporal_store(o1, (f32x4*)(crow + 4));
  }
#undef GATHER_RANGE
#undef FMA8
}

// ---------------------------------------------------------------------------
extern "C" void kernel_launch(void* const* d_in, const int* in_sizes, int n_in,
                              void* d_out, int out_size, void* d_ws, size_t ws_size,
                              hipStream_t stream) {
  const float* x = (const float*)d_in[0];  // [8192, 8192] f32
  const float* W = (const float*)d_in[1];  // [512, 8192]  f32
  float* out = (float*)d_out;              // [8192, 512]  f32
  __bf16* WT = (__bf16*)d_ws;              // [8192, 512]  bf16 (8 MB)

  void* args[] = {(void*)&x, (void*)&W, (void*)&WT, (void*)&out};
  hipLaunchCooperativeKernel((void*)spmm_coop, dim3(NBLK), dim3(256),
                             args, 0, stream);
}

// Round 11
// 103.067 us; speedup vs baseline: 2.4426x; 2.4426x over previous
//
#include <hip/hip_runtime.h>
#include <math.h>

#define M_ROWS 8192   // B*S
#define KDIM   8192   // V
#define NDIM   512    // D
#define RCAP   512    // LDS list slots per row (mean nnz 82, sigma 9)

typedef float    f32x4  __attribute__((ext_vector_type(4)));
typedef unsigned u32x4  __attribute__((ext_vector_type(4)));
typedef __bf16   bf16x8 __attribute__((ext_vector_type(8)));

// ---------------------------------------------------------------------------
// K1: W [512, 8192] f32 -> WT [8192, 512] bf16 (d_ws, 8 MB).  (R6-proven)
__global__ __launch_bounds__(256)
void transpose_w(const float* __restrict__ W, __bf16* __restrict__ WT) {
  __shared__ float tile[64][65];
  const int t  = threadIdx.x;
  const int v0 = (blockIdx.x & 127) << 6;
  const int d0 = (blockIdx.x >> 7) << 6;
  #pragma unroll
  for (int i = 0; i < 4; ++i) {
    int idx = i * 256 + t;
    int r = idx >> 4, c = (idx & 15) << 2;
    f32x4 val = *(const f32x4*)(W + (size_t)(d0 + r) * KDIM + v0 + c);
    tile[r][c + 0] = val.x; tile[r][c + 1] = val.y;
    tile[r][c + 2] = val.z; tile[r][c + 3] = val.w;
  }
  __syncthreads();
  #pragma unroll
  for (int i = 0; i < 2; ++i) {
    int idx = i * 256 + t;
    int vr = idx >> 3, d8 = (idx & 7) << 3;
    bf16x8 u;
    #pragma unroll
    for (int j = 0; j < 8; ++j) u[j] = (__bf16)tile[d8 + j][vr];
    *(bf16x8*)(WT + (size_t)(v0 + vr) * NDIM + d0 + d8) = u;
  }
}

// ---------------------------------------------------------------------------
// K2: fused scan + quarter-ordered gather. Grid = 2048 blocks x 256 thr =
// EXACTLY the resident capacity (8 blocks/CU) -> all waves co-start, no
// retirement stagger. Every wave: scan its row (equal duration), then gather
// v-quarters IN ORDER (0..3). Natural alignment keeps the grid-wide live
// gather set to ~one 2 MB WT slice per XCD L2 -> gathers served from L2
// instead of L3. Accumulators in registers across quarters (no C RMW).
// Exact at any density: ballot enumerates actual nonzeros; overflow (never
// at ~1%) -> exact full re-scan fallback.
__global__ __launch_bounds__(256, 8)
void spmm_qtr(const float* __restrict__ A, const __bf16* __restrict__ WT,
              float* __restrict__ C) {
  __shared__ unsigned lists[4][RCAP];   // 8 KB -> LDS not the occupancy cap
  const int lane = threadIdx.x & 63;
  const int w    = threadIdx.x >> 6;
  const int m    = blockIdx.x * 4 + w;
  const float* arow = A + (size_t)m * KDIM;
  unsigned* rl = &lists[w][0];
  const char* wtb = (const char*)WT;

  // ---- scan + compact, quarter-segmented (cumulative cuts at pos 7/15/23)
  const unsigned long long ltmask = (1ull << lane) - 1ull;
  unsigned cur = 0, q1 = 0, q2 = 0, q3 = 0;
  bool ovf = false;
  f32x4 bufs[4];
  #pragma unroll
  for (int p = 0; p < 4; ++p)
    bufs[p] = __builtin_nontemporal_load((const f32x4*)(arow + p * 256 + lane * 4));
  #pragma unroll 4
  for (int pos = 0; pos < 32; ++pos) {
    f32x4 av = bufs[pos & 3];
    if (pos + 4 < 32)
      bufs[pos & 3] = __builtin_nontemporal_load(
          (const f32x4*)(arow + (pos + 4) * 256 + lane * 4));
    #pragma unroll
    for (int j = 0; j < 4; ++j) {
      unsigned long long msk = __ballot(av[j] != 0.0f);
      if (msk == 0) continue;
      unsigned cnt = (unsigned)__popcll(msk);
      if (cur + cnt <= RCAP) {
        if (av[j] != 0.0f) {
          unsigned pre = (unsigned)__popcll(msk & ltmask);
          unsigned fb  = (__float_as_uint(av[j]) + 0x8000u) & 0xFFFF0000u;
          rl[cur + pre] = fb | (unsigned)(pos * 256 + lane * 4 + j);
        }
        cur += cnt;
      } else {
        ovf = true;   // statistically unreachable at ~1% density
      }
    }
    if (pos == 7)  q1 = cur;
    if (pos == 15) q2 = cur;
    if (pos == 23) q3 = cur;
  }

  float a0 = 0.f, a1 = 0.f, a2 = 0.f, a3 = 0.f,
        a4 = 0.f, a5 = 0.f, a6 = 0.f, a7 = 0.f;

#define FMA8(f, q)                                                          \
  {                                                                         \
    a0 = fmaf(f, __uint_as_float((q).x << 16), a0);                         \
    a1 = fmaf(f, __uint_as_float((q).x & 0xffff0000u), a1);                 \
    a2 = fmaf(f, __uint_as_float((q).y << 16), a2);                         \
    a3 = fmaf(f, __uint_as_float((q).y & 0xffff0000u), a3);                 \
    a4 = fmaf(f, __uint_as_float((q).z << 16), a4);                         \
    a5 = fmaf(f, __uint_as_float((q).z & 0xffff0000u), a5);                 \
    a6 = fmaf(f, __uint_as_float((q).w << 16), a6);                         \
    a7 = fmaf(f, __uint_as_float((q).w & 0xffff0000u), a7);                 \
  }

  if (!ovf) {
    // ---- gather, v-quarter by v-quarter (grid-aligned by construction)
    #pragma unroll
    for (int qtr = 0; qtr < 4; ++qtr) {
      const int beg = (qtr == 0) ? 0 : (qtr == 1 ? (int)q1 : (qtr == 2 ? (int)q2 : (int)q3));
      const int end = (qtr == 0) ? (int)q1 : (qtr == 1 ? (int)q2 : (qtr == 2 ? (int)q3 : (int)cur));
      for (int g = beg; g < end; g += 8) {
        unsigned pk[8];
        #pragma unroll
        for (int k = 0; k < 8; ++k)
          pk[k] = (g + k < end) ? rl[g + k] : 0u;   // pad: f=0,v=0 -> adds 0
        u32x4 qv[8];
        #pragma unroll
        for (int k = 0; k < 8; ++k)
          qv[k] = *(const u32x4*)(wtb + (size_t)(pk[k] & 8191u) * (NDIM * 2)
                                  + lane * 16);
        #pragma unroll
        for (int k = 0; k < 8; ++k) {
          float f = __uint_as_float(pk[k] & 0xFFFF0000u);
          FMA8(f, qv[k]);
        }
      }
    }
  } else {
    // exact fallback: full re-scan of the row
    for (int it = 0; it < KDIM / 256; ++it) {
      f32x4 av = *(const f32x4*)(arow + it * 256 + lane * 4);
      #pragma unroll
      for (int j = 0; j < 4; ++j) {
        unsigned long long msk = __ballot(av[j] != 0.0f);
        while (msk) {
          int s = __builtin_ctzll(msk); msk &= msk - 1;
          float f = __shfl(av[j], s, 64);
          int v = it * 256 + s * 4 + j;
          u32x4 q = *(const u32x4*)(wtb + (size_t)v * (NDIM * 2) + lane * 16);
          FMA8(f, q);
        }
      }
    }
  }

  float* crow = C + (size_t)m * NDIM + lane * 8;
  f32x4 o0 = {tanhf(a0), tanhf(a1), tanhf(a2), tanhf(a3)};
  f32x4 o1 = {tanhf(a4), tanhf(a5), tanhf(a6), tanhf(a7)};
  __builtin_nontemporal_store(o0, (f32x4*)(crow + 0));
  __builtin_nontemporal_store(o1, (f32x4*)(crow + 4));
#undef FMA8
}

// ---------------------------------------------------------------------------
extern "C" void kernel_launch(void* const* d_in, const int* in_sizes, int n_in,
                              void* d_out, int out_size, void* d_ws, size_t ws_size,
                              hipStream_t stream) {
  const float* x = (const float*)d_in[0];  // [8192, 8192] f32
  const float* W = (const float*)d_in[1];  // [512, 8192]  f32
  float* out = (float*)d_out;              // [8192, 512]  f32
  __bf16* WT = (__bf16*)d_ws;              // [8192, 512]  bf16 (8 MB)

  transpose_w<<<dim3(1024),       dim3(256), 0, stream>>>(W, WT);
  spmm_qtr   <<<dim3(M_ROWS / 4), dim3(256), 0, stream>>>(x, WT, out);
}